// Round 15
// baseline (84.160 us; speedup 1.0000x reference)
//
#include <hip/hip_runtime.h>

#define N 64
#define MARGIN 0.1f
#define WAVES_PER_BLOCK 4
#define NBLOCKS 2048

// closed form (verified R2..R14, absmax 0.0):
//   p_e = #{k: lab_k < lab_e},  u_e = sc_e - MARGIN*p_e
//   row_loss = sum_e u_e*(31.5 - p_e) + 0.25*sum_{e,k}|u_e - u_k|
//
// R15 = R14 minus the manual `s_waitcnt lgkmcnt(0)` fence. lgkmcnt covers
// SMEM *and* LDS: the asm fence (present since R2!) drained all outstanding
// s_load broadcast supply every row -- a per-row scheduling barrier that
// explains VALUBusy ~21% and why interleave/pipe-split changes were neutral.
// Same-wave ds_write->ds_read to the same address is in-order in HW, and the
// compiler inserts the minimal lgkmcnt(N) before the first use of each
// ds_read result. No barrier needed; let the scheduler pipeline s_loads.
__global__ __launch_bounds__(256) void mmrl_partial(const float* __restrict__ scores,
                                                    const float* __restrict__ labels,
                                                    float* __restrict__ partial,
                                                    int rows) {
    __shared__ float ubuf[WAVES_PER_BLOCK][N];
    __shared__ float wsum[WAVES_PER_BLOCK];

    const int lane = threadIdx.x & 63;
    const int w    = threadIdx.x >> 6;
    const int gwave = blockIdx.x * WAVES_PER_BLOCK + w;
    const int nwaves = NBLOCKS * WAVES_PER_BLOCK;

    float acc = 0.0f;

    for (int row = gwave; row < rows; row += nwaves) {
        const int base = __builtin_amdgcn_readfirstlane(row) * N;
        const float labv = labels[base + lane];   // coalesced per-lane copy
        const float scv  = scores[base + lane];

        // ---- pass 1: label rank p (SMEM float4 broadcasts; sign-bit counts) ----
        const float4* L4 = (const float4*)(labels + base);
        int p0 = 0, p1 = 0, p2 = 0, p3 = 0;       // accumulate 0 / -1
        #pragma unroll
        for (int kk = 0; kk < N / 4; ++kk) {
            const float4 a = L4[kk];
            p0 += __float_as_int(a.x - labv) >> 31;
            p1 += __float_as_int(a.y - labv) >> 31;
            p2 += __float_as_int(a.z - labv) >> 31;
            p3 += __float_as_int(a.w - labv) >> 31;
        }
        const int pv = -((p0 + p1) + (p2 + p3));

        const float u = fmaf(-MARGIN, (float)pv, scv);

        // ---- pass 2: sum_k |u - u_k| (LDS uniform float4 broadcasts) ----
        // Same-wave write->read: HW is in-order within a wave; compiler
        // inserts the minimal lgkmcnt before first use of each read.
        ubuf[w][lane] = u;
        const float4* U4 = (const float4*)ubuf[w];
        float A0 = 0.0f, A1 = 0.0f, A2 = 0.0f, A3 = 0.0f;
        #pragma unroll
        for (int kk = 0; kk < N / 4; ++kk) {
            const float4 a = U4[kk];
            A0 += fabsf(a.x - u);                  // v_sub + v_add with |..| mod
            A1 += fabsf(a.y - u);
            A2 += fabsf(a.z - u);
            A3 += fabsf(a.w - u);
        }
        const float rowabs = (A0 + A1) + (A2 + A3);

        // c = u*( (N-1)/2 - p ) + rowabs/4
        acc = fmaf(u, 31.5f - (float)pv, fmaf(0.25f, rowabs, acc));
    }

    // ---- wave reduction ----
    #pragma unroll
    for (int off = 32; off > 0; off >>= 1)
        acc += __shfl_down(acc, off, 64);

    if (lane == 0) wsum[w] = acc;
    __syncthreads();
    if (threadIdx.x == 0) {
        float s = 0.0f;
        #pragma unroll
        for (int i = 0; i < WAVES_PER_BLOCK; ++i) s += wsum[i];
        partial[blockIdx.x] = s;          // plain store, no atomic, no fence
    }
}

__global__ __launch_bounds__(256) void mmrl_reduce(const float* __restrict__ partial,
                                                   float* __restrict__ out,
                                                   int npartial, float inv_rows) {
    const int t = threadIdx.x;
    float s = 0.0f;
    for (int i = t; i < npartial; i += 256)
        s += partial[i];
    #pragma unroll
    for (int off = 32; off > 0; off >>= 1)
        s += __shfl_down(s, off, 64);
    __shared__ float wsum[4];
    if ((t & 63) == 0) wsum[t >> 6] = s;
    __syncthreads();
    if (t == 0)
        out[0] = (wsum[0] + wsum[1] + wsum[2] + wsum[3]) * inv_rows;
}

extern "C" void kernel_launch(void* const* d_in, const int* in_sizes, int n_in,
                              void* d_out, int out_size, void* d_ws, size_t ws_size,
                              hipStream_t stream) {
    const float* scores = (const float*)d_in[0];
    const float* labels = (const float*)d_in[1];
    float* out = (float*)d_out;
    float* partial = (float*)d_ws;        // 2048 floats = 8 KB << ws_size
    const int rows = in_sizes[0] / N;     // 32768

    mmrl_partial<<<NBLOCKS, 256, 0, stream>>>(scores, labels, partial, rows);
    mmrl_reduce<<<1, 256, 0, stream>>>(partial, out, NBLOCKS, 1.0f / (float)rows);
}